// Round 9
// baseline (188.029 us; speedup 1.0000x reference)
//
#include <hip/hip_runtime.h>
#include <hip/hip_bf16.h>
#include <stdint.h>

typedef unsigned short u16;
typedef __attribute__((ext_vector_type(8))) short bf16x8;
typedef __attribute__((ext_vector_type(4))) float f32x4;
typedef __attribute__((ext_vector_type(2))) unsigned int u32x2;

typedef const __attribute__((address_space(1))) unsigned int* gu32p;
typedef __attribute__((address_space(3))) unsigned int* lu32p;

__device__ __forceinline__ void gl_lds16(const u16* g, u16* l) {
  // async global->LDS DMA, 16B/lane, LDS dest = wave-uniform base + lane*16
  __builtin_amdgcn_global_load_lds((gu32p)(const void*)g, (lu32p)(void*)l, 16, 0, 0);
}

template<int N> __device__ __forceinline__ void wait_vmcnt() {
  if constexpr (N == 0)      asm volatile("s_waitcnt vmcnt(0)" ::: "memory");
  else if constexpr (N == 3) asm volatile("s_waitcnt vmcnt(3)" ::: "memory");
  else if constexpr (N == 4) asm volatile("s_waitcnt vmcnt(4)" ::: "memory");
  else                       asm volatile("s_waitcnt vmcnt(6)" ::: "memory");
}

__device__ __forceinline__ u16 f2bf(float f) {
  union { float f; unsigned u; } v; v.f = f;
  unsigned r = v.u + 0x7fffu + ((v.u >> 16) & 1u);
  return (u16)(r >> 16);
}
// packed f32x2 -> bf16x2 (one v_cvt_pk), scattered to two u16 slots
__device__ __forceinline__ void st2bf(u16* p0, u16* p1, float a, float b) {
  union { __hip_bfloat162 h; u16 u[2]; } cv;
  cv.h = __float22bfloat162_rn(make_float2(a, b));
  *p0 = cv.u[0]; *p1 = cv.u[1];
}
// packed f32x2 -> bf16x2 as one u32 word (low = a, high = b)
__device__ __forceinline__ unsigned pk2bf(float a, float b) {
  union { __hip_bfloat162 h; unsigned u; } cv;
  cv.h = __float22bfloat162_rn(make_float2(a, b));
  return cv.u;
}

// ---------------- fp32 -> bf16 convert (x + 4 weights) and RoPE cos/sin table
__global__ void convert_kernel(const float4* __restrict__ x, const float4* __restrict__ wq,
                               const float4* __restrict__ wk, const float4* __restrict__ wv,
                               const float4* __restrict__ wp,
                               u16* __restrict__ xb, u16* __restrict__ wqb, u16* __restrict__ wkb,
                               u16* __restrict__ wvb, u16* __restrict__ wpb,
                               float2* __restrict__ tab) {
  int i = blockIdx.x * 256 + threadIdx.x;
  const int NX = 1048576, NW = 262144, NCONV = NX + 4 * NW;
  if (i >= NCONV) {
    int j = i - NCONV;              // 0..65535 : t*32 + d
    int d = j & 31, t = j >> 5;
    float ang = (float)t * expf(-0.28782313662425572f * (float)d);  // ln(10000)/32
    tab[j] = make_float2(cosf(ang), sinf(ang));
    return;
  }
  const float4* src; u16* dst; int off;
  if (i < NX)            { src = x;  dst = xb;  off = i; }
  else if (i < NX + NW)  { src = wq; dst = wqb; off = i - NX; }
  else if (i < NX + 2*NW){ src = wk; dst = wkb; off = i - NX - NW; }
  else if (i < NX + 3*NW){ src = wv; dst = wvb; off = i - NX - 2*NW; }
  else                   { src = wp; dst = wpb; off = i - NX - 3*NW; }
  float4 v = src[off];
  ushort4 ov = make_ushort4(f2bf(v.x), f2bf(v.y), f2bf(v.z), f2bf(v.w));
  *(ushort4*)&dst[off * 4] = ov;
}

// ---------------- NT GEMM: C[M,N] = A[M,K] * B[N,K]^T + bias, K=1024, M=4096
// Tile BM x BN (wave grid 2x2), BK=32. R7: T4 counted-vmcnt 3-deep pipeline —
// triple-buffered LDS, raw s_barrier, NEVER vmcnt(0) in the main loop.
// Per step k: vmcnt(LOADS) [my stage-k done; stage-k+1 in flight] -> s_barrier
// [everyone's stage-k done; everyone's k-1 ds_reads done (their lgkm waits
// precede their barrier)] -> issue stage(k+2) [safe: after the barrier ending
// step k-1's reads of buf (k+2)%3] -> ds_read/MFMA buf k%3. Each load gets
// ~2 steps of latency cover; no full drain (R6 lesson: the per-step
// vmcnt(0)+barrier drain is THE bottleneck; more/smaller domains made it
// worse: 46.8 -> 55.7 us at BM=64). R7 verified: QKV 46.8 -> <44.4 us.
// T1: bijective XCD swizzle. T2-lite: granule swizzle quad^((row>>1)&3)
// (conflicts 3.1M -> 0, R5); src column pre-swizzled, LDS dest linear.
// FUSE_ROPE: rotary in epilogue for z<2 (needs BN=128); z==0 (Q) pre-scales
// by (1/sqrt(64))*log2(e). TRANS_V: z==2 stores Vt[(b*1024+c)*2048+t].
template<int FUSE_ROPE, int OUT_BF16, int TRANS_V, int BM, int BN, int NZ>
__global__ __launch_bounds__(256) void gemm_bt_kernel(
    const u16* __restrict__ A,
    const u16* __restrict__ B0, const u16* __restrict__ B1, const u16* __restrict__ B2,
    const float* __restrict__ bias0, const float* __restrict__ bias1, const float* __restrict__ bias2,
    void* out0, void* out1, void* out2, const float2* __restrict__ tab)
{
  const int MT = BM / 32, NT = BN / 32;       // per-wave frags (wave grid 2x2)
  const int LOADS = BM / 64 + BN / 64;        // gl_lds ops per wave per step
  __shared__ __align__(16) u16 As[3][BM * 32];
  __shared__ __align__(16) u16 Bs[3][BN * 32];

  // T1 XCD swizzle: contiguous chunk of new ids per XCD
  const int NXg = 1024 / BN, NYg = 4096 / BM;
  const int nwg = NXg * NYg * NZ;
  const int wgid = blockIdx.x + NXg * (blockIdx.y + NYg * blockIdx.z);
  const int swz = (wgid & 7) * (nwg >> 3) + (wgid >> 3);
  const int bx = swz % NXg, by = (swz / NXg) % NYg, z = swz / (NXg * NYg);

  const u16* Bw = (z == 0) ? B0 : (z == 1) ? B1 : B2;
  const float* bias = (z == 0) ? bias0 : (z == 1) ? bias1 : bias2;
  void* outv = (z == 0) ? out0 : (z == 1) ? out1 : out2;
  const int tid = threadIdx.x, lane = tid & 63, w = tid >> 6;
  const int wr = w >> 1, wc = w & 1;
  const int quad = lane >> 4, l15 = lane & 15;
  const int m0 = by * BM, n0 = bx * BN;
  const int sr = lane >> 2;
  const int sg = ((lane & 3) ^ ((lane >> 3) & 3)) * 8;   // pre-swizzled src granule
  const int rg4 = (l15 >> 1) & 3;                        // read-side XOR key

  auto stg = [&](int kt, int bf) {
    const int k0 = kt * 32;
    #pragma unroll
    for (int p = 0; p < BM/64; p++)
      gl_lds16(A  + (m0 + p*64 + w*16 + sr) * 1024 + k0 + sg, &As[bf][p*2048 + w*512]);
    #pragma unroll
    for (int p = 0; p < BN/64; p++)
      gl_lds16(Bw + (n0 + p*64 + w*16 + sr) * 1024 + k0 + sg, &Bs[bf][p*2048 + w*512]);
  };

  f32x4 acc[MT][NT] = {};
  stg(0, 0);
  stg(1, 1);
  int cur = 0;
  for (int kt = 0; kt < 32; kt++) {
    __builtin_amdgcn_sched_barrier(0);
    if (kt < 31) wait_vmcnt<LOADS>();    // stage-k landed; k+1 stays in flight
    else         wait_vmcnt<0>();        // last tile: nothing newer to leave
    __builtin_amdgcn_sched_barrier(0);
    __builtin_amdgcn_s_barrier();
    __builtin_amdgcn_sched_barrier(0);
    if (kt < 30) stg(kt + 2, cur == 0 ? 2 : cur - 1);   // buf (kt+2)%3
    const int bf = cur;
    bf16x8 af[MT], bfr[NT];
    #pragma unroll
    for (int mt = 0; mt < MT; mt++)
      af[mt] = *(const bf16x8*)&As[bf][(wr*(BM/2) + mt*16 + l15) * 32 + (quad ^ rg4) * 8];
    #pragma unroll
    for (int nt = 0; nt < NT; nt++)
      bfr[nt] = *(const bf16x8*)&Bs[bf][(wc*(BN/2) + nt*16 + l15) * 32 + (quad ^ rg4) * 8];
    #pragma unroll
    for (int mt = 0; mt < MT; mt++)
      #pragma unroll
      for (int nt = 0; nt < NT; nt++)
        acc[mt][nt] = __builtin_amdgcn_mfma_f32_16x16x32_bf16(af[mt], bfr[nt], acc[mt][nt], 0, 0, 0);
    cur = (cur == 2) ? 0 : cur + 1;
  }

  if (TRANS_V && z == 2) {
    // direct transposed store: lane holds 4 consecutive t (quad*4+r) for col c
    const int bb = m0 >> 11, tg0 = (m0 & 2047) + wr*(BM/2) + quad*4;
    #pragma unroll
    for (int nt = 0; nt < NT; nt++) {
      const int c = n0 + wc*(BN/2) + nt*16 + l15;
      const float bv = bias[c];
      u16* vrow = (u16*)outv + (size_t)(bb*1024 + c) * 2048 + tg0;
      #pragma unroll
      for (int mt = 0; mt < MT; mt++) {
        ushort4 pk;
        pk.x = f2bf(acc[mt][nt][0] + bv); pk.y = f2bf(acc[mt][nt][1] + bv);
        pk.z = f2bf(acc[mt][nt][2] + bv); pk.w = f2bf(acc[mt][nt][3] + bv);
        *(ushort4*)&vrow[mt*16] = pk;
      }
    }
    return;
  }

  #pragma unroll
  for (int mt = 0; mt < MT; mt++) {
    #pragma unroll
    for (int r = 0; r < 4; r++) {
      const int row = m0 + wr*(BM/2) + mt*16 + quad*4 + r;
      float v[NT];
      #pragma unroll
      for (int nt = 0; nt < NT; nt++)
        v[nt] = acc[mt][nt][r] + bias[n0 + wc*(BN/2) + nt*16 + l15];
      if (FUSE_ROPE && z < 2) {
        const int t = row & 2047;
        #pragma unroll
        for (int nt = 0; nt < 2; nt++) {
          const int d = nt*16 + l15;
          float2 cs = tab[t*32 + d];
          float x0 = v[nt], x1 = v[nt+2];
          v[nt]   = x0 * cs.x - x1 * cs.y;
          v[nt+2] = x1 * cs.x + x0 * cs.y;
        }
        if (z == 0) {
          // fold (1/sqrt(64))*log2(e) into Q: attention then does exp2(s) raw
          const float SC = 0.18033688011112042f;
          #pragma unroll
          for (int nt = 0; nt < NT; nt++) v[nt] *= SC;
        }
      }
      #pragma unroll
      for (int nt = 0; nt < NT; nt++) {
        const int col = n0 + wc*(BN/2) + nt*16 + l15;
        if (OUT_BF16) ((u16*)outv)[row * 1024 + col] = f2bf(v[nt]);
        else          ((float*)outv)[row * 1024 + col] = v[nt];
      }
    }
  }
}

// ---------------- causal flash attention. R9: one 64-row q-tile per 4-wave
// block, KVBLK=64, LDS 32KB/block -> grid (32,16,2) = 1024 blocks = FOUR
// blocks/CU = 4 waves/SIMD: 2x the TLP of the 128-row version. R8 post-mortem:
// attn is latency-bound on the per-wave serial chain (MFMA~25%, LDS-pipe~25%
// of CU cycles, nothing saturated at 2 waves/SIMD); more peer waves fill the
// dependency gaps, and 4 independent barrier domains overlap each other's
// stage drains (drain ~300cyc L2-resident vs ~350cyc compute/stripe/SIMD,
// x4 domains ~saturates — unlike R6's HBM-latency GEMM trap).
// Balance: co-resident {c,c+256,c+512,c+768} -> tiles {31-x,31-x,x,x} via
// t = b ? x : 31-x -> 66 stripes per CU uniformly.
// Plain __syncthreads + double buffer (R8: counted-vmcnt is NULL for attn).
//
// T12 (in-register P): QK^T computed with SWAPPED operands, mfma(K, Q):
// D transposes to S[q=l15][k=nt*16+quad*4+r]; permlane32_swap +
// permlane16_swap repack straight into the PV A-frag. P never touches LDS.
// Q arrives pre-scaled by (1/sqrt(64))*log2(e) (GEMM epilogue), so
// p = exp2(s) directly via __builtin_amdgcn_exp2f (bare v_exp_f32).
// T5: s_setprio(1) around MFMA clusters.
__global__ __launch_bounds__(256) void attn_kernel(
    const u16* __restrict__ qg, const u16* __restrict__ kg,
    const u16* __restrict__ vtg, u16* __restrict__ yg)
{
  __shared__ __align__(16) u16 K_lds[2][64 * 64];      // [s][d], swizzle g^(s&7)
  __shared__ __align__(16) u16 V_lds[2][64 * 64];      // [d][s], swizzle g^(d&7)
  const int x = blockIdx.x;                // 0..31
  const int hh = blockIdx.y, b = blockIdx.z;
  const int t = b ? x : (31 - x);          // heavy/light complement per CU slot
  const int tid = threadIdx.x, lane = tid & 63, w = tid >> 6;   // w: 0..3
  const int quad = lane >> 4, l15 = lane & 15;
  const int bh = b * (2048 * 1024) + hh * 64;
  const int vtb = (b * 16 + hh) * 131072;  // Vt: [b,h][64 d][2048 t]

  bf16x8 qf[2];                            // wave owns 16 q-rows: t*64+w*16+l15
  const int qrow = t*64 + w*16 + l15;
  qf[0] = *(const bf16x8*)&qg[bh + qrow*1024 + quad*8];
  qf[1] = *(const bf16x8*)&qg[bh + qrow*1024 + 32 + quad*8];

  f32x4 o[4] = {};        // [dt] un-normalized output
  f32x4 l5 = {};          // row-sum accumulator (replicated across cols)

  bf16x8 ones;
  #pragma unroll
  for (int i2 = 0; i2 < 8; i2++) ones[i2] = (short)0x3F80;  // bf16 1.0

  auto do_stage = [&](int j, int bf) {
    #pragma unroll
    for (int p = 0; p < 2; p++) {          // K: 8 segs of 1024B (8 rows x 64)
      const int seg = w*2 + p;             // 0..7
      const int r = seg*8 + (lane >> 3);   // kv row 0..63
      const int g = (lane & 7) ^ (r & 7);
      gl_lds16(kg + bh + (j*64 + r) * 1024 + g*8, &K_lds[bf][seg*512]);
    }
    #pragma unroll
    for (int p = 0; p < 2; p++) {          // Vt: 8 segs of 8 d-rows x 64
      const int seg = w*2 + p;
      const int r = seg*8 + (lane >> 3);   // d row 0..63
      const int g = (lane & 7) ^ (r & 7);
      gl_lds16(vtg + vtb + r * 2048 + j*64 + g*8, &V_lds[bf][seg*512]);
    }
  };

  do_stage(0, 0);
  for (int j = 0; j <= t; j++) {
    __syncthreads();                       // stripe j landed; other buf free
    if (j < t) do_stage(j + 1, (j + 1) & 1);
    const int bf = j & 1;
    const bool diag = (j == t);

    // fused per-32-k-chunk pipeline: S^T -> mask -> exp2 -> pack -> PV
    #pragma unroll
    for (int ss = 0; ss < 2; ss++) {
      // ---- S^T = K Q^T for nt = 2ss, 2ss+1
      f32x4 s[2];
      #pragma unroll
      for (int h = 0; h < 2; h++) {
        const int nt = ss*2 + h;
        const int krow = (nt*16 + l15) * 64;
        const int g0 = ((quad)     ^ (l15 & 7)) * 8;
        const int g1 = ((4 + quad) ^ (l15 & 7)) * 8;
        bf16x8 kf0 = *(const bf16x8*)&K_lds[bf][krow + g0];
        bf16x8 kf1 = *(const bf16x8*)&K_lds[bf][krow + g1];
        __builtin_amdgcn_s_setprio(1);
        f32x4 z = {};
        z = __builtin_amdgcn_mfma_f32_16x16x32_bf16(kf0, qf[0], z, 0, 0, 0);
        z = __builtin_amdgcn_mfma_f32_16x16x32_bf16(kf1, qf[1], z, 0, 0, 0);
        s[h] = z;
        __builtin_amdgcn_s_setprio(0);
      }
      if (diag) {
        const int qr = w*16 + l15;         // q-local (col axis of S^T)
        #pragma unroll
        for (int h = 0; h < 2; h++)
          #pragma unroll
          for (int r = 0; r < 4; r++)
            if ((ss*2 + h)*16 + quad*4 + r > qr) s[h][r] = -1e30f;
      }
      // ---- p = exp2(s); pack to PV A-frag in-register (no LDS)
      float a0 = __builtin_amdgcn_exp2f(s[0][0]), a1 = __builtin_amdgcn_exp2f(s[0][1]);
      float a2 = __builtin_amdgcn_exp2f(s[0][2]), a3 = __builtin_amdgcn_exp2f(s[0][3]);
      float b0 = __builtin_amdgcn_exp2f(s[1][0]), b1 = __builtin_amdgcn_exp2f(s[1][1]);
      float b2 = __builtin_amdgcn_exp2f(s[1][2]), b3 = __builtin_amdgcn_exp2f(s[1][3]);
      unsigned A01 = pk2bf(a0, a1), A23 = pk2bf(a2, a3);
      unsigned B01 = pk2bf(b0, b1), B23 = pk2bf(b2, b3);
      // permlane32_swap: r0=[X_lo,Y_lo], r1=[X_hi,Y_hi]
      // permlane16_swap: r0=[Xq0,Yq0,Xq2,Yq2], r1=[Xq1,Yq1,Xq3,Yq3]
      u32x2 t0 = __builtin_amdgcn_permlane32_swap(A01, B01, false, false);
      u32x2 w02 = __builtin_amdgcn_permlane16_swap(t0[0], t0[1], false, false);
      u32x2 t1 = __builtin_amdgcn_permlane32_swap(A23, B23, false, false);
      u32x2 w13 = __builtin_amdgcn_permlane16_swap(t1[0], t1[1], false, false);
      union { unsigned u[4]; bf16x8 v; } pk;
      pk.u[0] = w02[0]; pk.u[1] = w13[0]; pk.u[2] = w02[1]; pk.u[3] = w13[1];
      bf16x8 pa = pk.v;
      // ---- O += P V ; l += P 1
      __builtin_amdgcn_s_setprio(1);
      l5 = __builtin_amdgcn_mfma_f32_16x16x32_bf16(pa, ones, l5, 0, 0, 0);
      #pragma unroll
      for (int dt = 0; dt < 4; dt++) {
        const int vg = ((ss*4 + quad) ^ (l15 & 7)) * 8;
        bf16x8 vf = *(const bf16x8*)&V_lds[bf][(dt*16 + l15)*64 + vg];
        o[dt] = __builtin_amdgcn_mfma_f32_16x16x32_bf16(pa, vf, o[dt], 0, 0, 0);
      }
      __builtin_amdgcn_s_setprio(0);
    }
  }

  #pragma unroll
  for (int r = 0; r < 4; r++) {
    float inv = 1.0f / l5[r];
    u16* yr = &yg[bh + (t*64 + w*16 + quad*4 + r) * 1024 + l15];
    st2bf(yr,      yr + 16, o[0][r] * inv, o[1][r] * inv);
    st2bf(yr + 32, yr + 48, o[2][r] * inv, o[3][r] * inv);
  }
}

extern "C" void kernel_launch(void* const* d_in, const int* in_sizes, int n_in,
                              void* d_out, int out_size, void* d_ws, size_t ws_size,
                              hipStream_t stream) {
  const float* x  = (const float*)d_in[0];
  const float* Wq = (const float*)d_in[1];
  const float* bq = (const float*)d_in[2];
  const float* Wk = (const float*)d_in[3];
  const float* bk = (const float*)d_in[4];
  const float* Wv = (const float*)d_in[5];
  const float* bv = (const float*)d_in[6];
  const float* Wp = (const float*)d_in[7];
  const float* bp = (const float*)d_in[8];

  char* ws = (char*)d_ws;
  u16* xb  = (u16*)(ws);                   // 8 MB, reused as attention output y
  u16* wqb = (u16*)(ws + (8u  << 20));
  u16* wkb = (u16*)(ws + (10u << 20));
  u16* wvb = (u16*)(ws + (12u << 20));
  u16* wpb = (u16*)(ws + (14u << 20));
  u16* qb  = (u16*)(ws + (16u << 20));
  u16* kb  = (u16*)(ws + (24u << 20));
  u16* vtb = (u16*)(ws + (32u << 20));     // V transposed: [b,h,d][t], 8 MB
  float2* tab = (float2*)(ws + (40u << 20));
  u16* yb = xb;

  convert_kernel<<<8448, 256, 0, stream>>>((const float4*)x, (const float4*)Wq, (const float4*)Wk,
                                           (const float4*)Wv, (const float4*)Wp,
                                           xb, wqb, wkb, wvb, wpb, tab);
  gemm_bt_kernel<1, 1, 1, 128, 128, 3><<<dim3(8, 32, 3), 256, 0, stream>>>(
      xb, wqb, wkb, wvb, bq, bk, bv, (void*)qb, (void*)kb, (void*)vtb, tab);
  attn_kernel<<<dim3(32, 16, 2), 256, 0, stream>>>(qb, kb, vtb, yb);
  gemm_bt_kernel<0, 0, 0, 128, 64, 1><<<dim3(16, 32, 1), 256, 0, stream>>>(
      yb, wpb, wpb, wpb, bp, bp, bp, (void*)d_out, (void*)d_out, (void*)d_out, tab);
}

// Round 10
// 183.148 us; speedup vs baseline: 1.0267x; 1.0267x over previous
//
#include <hip/hip_runtime.h>
#include <hip/hip_bf16.h>
#include <stdint.h>

typedef unsigned short u16;
typedef __attribute__((ext_vector_type(8))) short bf16x8;
typedef __attribute__((ext_vector_type(4))) float f32x4;
typedef __attribute__((ext_vector_type(2))) unsigned int u32x2;

typedef const __attribute__((address_space(1))) unsigned int* gu32p;
typedef __attribute__((address_space(3))) unsigned int* lu32p;

__device__ __forceinline__ void gl_lds16(const u16* g, u16* l) {
  // async global->LDS DMA, 16B/lane, LDS dest = wave-uniform base + lane*16
  __builtin_amdgcn_global_load_lds((gu32p)(const void*)g, (lu32p)(void*)l, 16, 0, 0);
}

template<int N> __device__ __forceinline__ void wait_vmcnt() {
  if constexpr (N == 0)      asm volatile("s_waitcnt vmcnt(0)" ::: "memory");
  else if constexpr (N == 3) asm volatile("s_waitcnt vmcnt(3)" ::: "memory");
  else if constexpr (N == 4) asm volatile("s_waitcnt vmcnt(4)" ::: "memory");
  else                       asm volatile("s_waitcnt vmcnt(6)" ::: "memory");
}

__device__ __forceinline__ u16 f2bf(float f) {
  union { float f; unsigned u; } v; v.f = f;
  unsigned r = v.u + 0x7fffu + ((v.u >> 16) & 1u);
  return (u16)(r >> 16);
}
// packed f32x2 -> bf16x2 (one v_cvt_pk), scattered to two u16 slots
__device__ __forceinline__ void st2bf(u16* p0, u16* p1, float a, float b) {
  union { __hip_bfloat162 h; u16 u[2]; } cv;
  cv.h = __float22bfloat162_rn(make_float2(a, b));
  *p0 = cv.u[0]; *p1 = cv.u[1];
}
// packed f32x2 -> bf16x2 as one u32 word (low = a, high = b)
__device__ __forceinline__ unsigned pk2bf(float a, float b) {
  union { __hip_bfloat162 h; unsigned u; } cv;
  cv.h = __float22bfloat162_rn(make_float2(a, b));
  return cv.u;
}

// ---------------- fp32 -> bf16 convert (x + 4 weights) and RoPE cos/sin table
__global__ void convert_kernel(const float4* __restrict__ x, const float4* __restrict__ wq,
                               const float4* __restrict__ wk, const float4* __restrict__ wv,
                               const float4* __restrict__ wp,
                               u16* __restrict__ xb, u16* __restrict__ wqb, u16* __restrict__ wkb,
                               u16* __restrict__ wvb, u16* __restrict__ wpb,
                               float2* __restrict__ tab) {
  int i = blockIdx.x * 256 + threadIdx.x;
  const int NX = 1048576, NW = 262144, NCONV = NX + 4 * NW;
  if (i >= NCONV) {
    int j = i - NCONV;              // 0..65535 : t*32 + d
    int d = j & 31, t = j >> 5;
    float ang = (float)t * expf(-0.28782313662425572f * (float)d);  // ln(10000)/32
    tab[j] = make_float2(cosf(ang), sinf(ang));
    return;
  }
  const float4* src; u16* dst; int off;
  if (i < NX)            { src = x;  dst = xb;  off = i; }
  else if (i < NX + NW)  { src = wq; dst = wqb; off = i - NX; }
  else if (i < NX + 2*NW){ src = wk; dst = wkb; off = i - NX - NW; }
  else if (i < NX + 3*NW){ src = wv; dst = wvb; off = i - NX - 2*NW; }
  else                   { src = wp; dst = wpb; off = i - NX - 3*NW; }
  float4 v = src[off];
  ushort4 ov = make_ushort4(f2bf(v.x), f2bf(v.y), f2bf(v.z), f2bf(v.w));
  *(ushort4*)&dst[off * 4] = ov;
}

// ---------------- NT GEMM: C[M,N] = A[M,K] * B[N,K]^T + bias, K=1024, M=4096
// Tile BM x BN (wave grid 2x2), K-step BK. T4 counted-vmcnt 3-deep pipeline —
// triple-buffered LDS, raw s_barrier, NEVER vmcnt(0) in the main loop
// (R7: QKV 46.8 -> 42.4 us; R6: per-step full drain was THE bottleneck).
// R10: BK is a template param. Proj (BN=64) uses BK=64: halves the barrier
// events (16 vs 32) and doubles compute per event (16 MFMA/wave/step) —
// R9 showed proj at 203 TF vs QKV 608 TF because 8 MFMAs/step couldn't
// hide the fixed per-step {vmcnt+barrier+stage} cost. LDS 72KB -> 2/CU.
// QKV keeps BK=32 (BK=64 would need 96KB -> 1 block/CU trap).
// T1: bijective XCD swizzle. T2-lite swizzles (conflicts 0, R5):
//   BK=32: granule quad^((l15>>1)&3), src pre-swizzled (lane&3)^((lane>>3)&3).
//   BK=64: granule (kk*4+quad)^(l15&7), src pre-swizzled (lane&7)^(lane>>3).
//   Both are <=2-way per 16-lane phase (free, m136); LDS dest stays linear
//   (global_load_lds constraint), source column carries the XOR (involution).
// FUSE_ROPE: rotary in epilogue for z<2 (needs BN=128); z==0 (Q) pre-scales
// by (1/sqrt(64))*log2(e). TRANS_V: z==2 stores Vt[(b*1024+c)*2048+t].
template<int FUSE_ROPE, int OUT_BF16, int TRANS_V, int BM, int BN, int BK, int NZ>
__global__ __launch_bounds__(256) void gemm_bt_kernel(
    const u16* __restrict__ A,
    const u16* __restrict__ B0, const u16* __restrict__ B1, const u16* __restrict__ B2,
    const float* __restrict__ bias0, const float* __restrict__ bias1, const float* __restrict__ bias2,
    void* out0, void* out1, void* out2, const float2* __restrict__ tab)
{
  const int MT = BM / 32, NT = BN / 32;       // per-wave frags (wave grid 2x2)
  const int LOADS = (BK == 32) ? (BM/64 + BN/64) : (BM/32 + BN/32);
  const int NSTEP = 1024 / BK;
  __shared__ __align__(16) u16 As[3][BM * BK];
  __shared__ __align__(16) u16 Bs[3][BN * BK];

  // T1 XCD swizzle: contiguous chunk of new ids per XCD
  const int NXg = 1024 / BN, NYg = 4096 / BM;
  const int nwg = NXg * NYg * NZ;
  const int wgid = blockIdx.x + NXg * (blockIdx.y + NYg * blockIdx.z);
  const int swz = (wgid & 7) * (nwg >> 3) + (wgid >> 3);
  const int bx = swz % NXg, by = (swz / NXg) % NYg, z = swz / (NXg * NYg);

  const u16* Bw = (z == 0) ? B0 : (z == 1) ? B1 : B2;
  const float* bias = (z == 0) ? bias0 : (z == 1) ? bias1 : bias2;
  void* outv = (z == 0) ? out0 : (z == 1) ? out1 : out2;
  const int tid = threadIdx.x, lane = tid & 63, w = tid >> 6;
  const int wr = w >> 1, wc = w & 1;
  const int quad = lane >> 4, l15 = lane & 15;
  const int m0 = by * BM, n0 = bx * BN;
  const int sr = lane >> 2;                              // BK=32 staging row
  const int sg = ((lane & 3) ^ ((lane >> 3) & 3)) * 8;   // BK=32 src granule
  const int sr64 = lane >> 3;                            // BK=64 staging row
  const int sg64 = ((lane & 7) ^ (lane >> 3)) * 8;       // BK=64 src granule
  const int rg4 = (l15 >> 1) & 3;                        // BK=32 read XOR key

  auto stg = [&](int kt, int bf) {
    const int k0 = kt * BK;
    if constexpr (BK == 32) {
      #pragma unroll
      for (int p = 0; p < BM/64; p++)
        gl_lds16(A  + (m0 + p*64 + w*16 + sr) * 1024 + k0 + sg, &As[bf][p*2048 + w*512]);
      #pragma unroll
      for (int p = 0; p < BN/64; p++)
        gl_lds16(Bw + (n0 + p*64 + w*16 + sr) * 1024 + k0 + sg, &Bs[bf][p*2048 + w*512]);
    } else {
      #pragma unroll
      for (int p = 0; p < BM/32; p++)
        gl_lds16(A  + (m0 + p*32 + w*8 + sr64) * 1024 + k0 + sg64, &As[bf][p*2048 + w*512]);
      #pragma unroll
      for (int p = 0; p < BN/32; p++)
        gl_lds16(Bw + (n0 + p*32 + w*8 + sr64) * 1024 + k0 + sg64, &Bs[bf][p*2048 + w*512]);
    }
  };

  f32x4 acc[MT][NT] = {};
  stg(0, 0);
  stg(1, 1);
  int cur = 0;
  for (int kt = 0; kt < NSTEP; kt++) {
    __builtin_amdgcn_sched_barrier(0);
    if (kt < NSTEP-1) wait_vmcnt<LOADS>();  // stage-k landed; k+1 in flight
    else              wait_vmcnt<0>();      // last tile: nothing newer to leave
    __builtin_amdgcn_sched_barrier(0);
    __builtin_amdgcn_s_barrier();
    __builtin_amdgcn_sched_barrier(0);
    if (kt < NSTEP-2) stg(kt + 2, cur == 0 ? 2 : cur - 1);   // buf (kt+2)%3
    const int bf = cur;
    if constexpr (BK == 32) {
      bf16x8 af[MT], bfr[NT];
      #pragma unroll
      for (int mt = 0; mt < MT; mt++)
        af[mt] = *(const bf16x8*)&As[bf][(wr*(BM/2) + mt*16 + l15) * 32 + (quad ^ rg4) * 8];
      #pragma unroll
      for (int nt = 0; nt < NT; nt++)
        bfr[nt] = *(const bf16x8*)&Bs[bf][(wc*(BN/2) + nt*16 + l15) * 32 + (quad ^ rg4) * 8];
      #pragma unroll
      for (int mt = 0; mt < MT; mt++)
        #pragma unroll
        for (int nt = 0; nt < NT; nt++)
          acc[mt][nt] = __builtin_amdgcn_mfma_f32_16x16x32_bf16(af[mt], bfr[nt], acc[mt][nt], 0, 0, 0);
    } else {
      #pragma unroll
      for (int kk = 0; kk < 2; kk++) {
        bf16x8 af[MT], bfr[NT];
        #pragma unroll
        for (int mt = 0; mt < MT; mt++)
          af[mt] = *(const bf16x8*)&As[bf][(wr*(BM/2) + mt*16 + l15) * 64 + ((kk*4 + quad) ^ (l15 & 7)) * 8];
        #pragma unroll
        for (int nt = 0; nt < NT; nt++)
          bfr[nt] = *(const bf16x8*)&Bs[bf][(wc*(BN/2) + nt*16 + l15) * 64 + ((kk*4 + quad) ^ (l15 & 7)) * 8];
        #pragma unroll
        for (int mt = 0; mt < MT; mt++)
          #pragma unroll
          for (int nt = 0; nt < NT; nt++)
            acc[mt][nt] = __builtin_amdgcn_mfma_f32_16x16x32_bf16(af[mt], bfr[nt], acc[mt][nt], 0, 0, 0);
      }
    }
    cur = (cur == 2) ? 0 : cur + 1;
  }

  if (TRANS_V && z == 2) {
    // direct transposed store: lane holds 4 consecutive t (quad*4+r) for col c
    const int bb = m0 >> 11, tg0 = (m0 & 2047) + wr*(BM/2) + quad*4;
    #pragma unroll
    for (int nt = 0; nt < NT; nt++) {
      const int c = n0 + wc*(BN/2) + nt*16 + l15;
      const float bv = bias[c];
      u16* vrow = (u16*)outv + (size_t)(bb*1024 + c) * 2048 + tg0;
      #pragma unroll
      for (int mt = 0; mt < MT; mt++) {
        ushort4 pk;
        pk.x = f2bf(acc[mt][nt][0] + bv); pk.y = f2bf(acc[mt][nt][1] + bv);
        pk.z = f2bf(acc[mt][nt][2] + bv); pk.w = f2bf(acc[mt][nt][3] + bv);
        *(ushort4*)&vrow[mt*16] = pk;
      }
    }
    return;
  }

  #pragma unroll
  for (int mt = 0; mt < MT; mt++) {
    #pragma unroll
    for (int r = 0; r < 4; r++) {
      const int row = m0 + wr*(BM/2) + mt*16 + quad*4 + r;
      float v[NT];
      #pragma unroll
      for (int nt = 0; nt < NT; nt++)
        v[nt] = acc[mt][nt][r] + bias[n0 + wc*(BN/2) + nt*16 + l15];
      if (FUSE_ROPE && z < 2) {
        const int t = row & 2047;
        #pragma unroll
        for (int nt = 0; nt < 2; nt++) {
          const int d = nt*16 + l15;
          float2 cs = tab[t*32 + d];
          float x0 = v[nt], x1 = v[nt+2];
          v[nt]   = x0 * cs.x - x1 * cs.y;
          v[nt+2] = x1 * cs.x + x0 * cs.y;
        }
        if (z == 0) {
          // fold (1/sqrt(64))*log2(e) into Q: attention then does exp2(s) raw
          const float SC = 0.18033688011112042f;
          #pragma unroll
          for (int nt = 0; nt < NT; nt++) v[nt] *= SC;
        }
      }
      #pragma unroll
      for (int nt = 0; nt < NT; nt++) {
        const int col = n0 + wc*(BN/2) + nt*16 + l15;
        if (OUT_BF16) ((u16*)outv)[row * 1024 + col] = f2bf(v[nt]);
        else          ((float*)outv)[row * 1024 + col] = v[nt];
      }
    }
  }
}

// ---------------- causal flash attention. R9: one 64-row q-tile per 4-wave
// block, KVBLK=64, LDS 32KB/block -> grid (32,16,2) = 1024 blocks = FOUR
// blocks/CU = 4 waves/SIMD (2x TLP; attn 45.2 -> <42.2 us). 4 independent
// barrier domains overlap each other's stage drains.
// Balance: co-resident {c,c+256,c+512,c+768} -> tiles {31-x,31-x,x,x} via
// t = b ? x : 31-x -> 66 stripes per CU uniformly.
// Plain __syncthreads + double buffer (R8: counted-vmcnt is NULL for attn).
//
// T12 (in-register P): QK^T computed with SWAPPED operands, mfma(K, Q):
// D transposes to S[q=l15][k=nt*16+quad*4+r]; permlane32_swap +
// permlane16_swap repack straight into the PV A-frag. P never touches LDS.
// Q arrives pre-scaled by (1/sqrt(64))*log2(e) (GEMM epilogue), so
// p = exp2(s) directly via __builtin_amdgcn_exp2f (bare v_exp_f32).
// T5: s_setprio(1) around MFMA clusters.
__global__ __launch_bounds__(256) void attn_kernel(
    const u16* __restrict__ qg, const u16* __restrict__ kg,
    const u16* __restrict__ vtg, u16* __restrict__ yg)
{
  __shared__ __align__(16) u16 K_lds[2][64 * 64];      // [s][d], swizzle g^(s&7)
  __shared__ __align__(16) u16 V_lds[2][64 * 64];      // [d][s], swizzle g^(d&7)
  const int x = blockIdx.x;                // 0..31
  const int hh = blockIdx.y, b = blockIdx.z;
  const int t = b ? x : (31 - x);          // heavy/light complement per CU slot
  const int tid = threadIdx.x, lane = tid & 63, w = tid >> 6;   // w: 0..3
  const int quad = lane >> 4, l15 = lane & 15;
  const int bh = b * (2048 * 1024) + hh * 64;
  const int vtb = (b * 16 + hh) * 131072;  // Vt: [b,h][64 d][2048 t]

  bf16x8 qf[2];                            // wave owns 16 q-rows: t*64+w*16+l15
  const int qrow = t*64 + w*16 + l15;
  qf[0] = *(const bf16x8*)&qg[bh + qrow*1024 + quad*8];
  qf[1] = *(const bf16x8*)&qg[bh + qrow*1024 + 32 + quad*8];

  f32x4 o[4] = {};        // [dt] un-normalized output
  f32x4 l5 = {};          // row-sum accumulator (replicated across cols)

  bf16x8 ones;
  #pragma unroll
  for (int i2 = 0; i2 < 8; i2++) ones[i2] = (short)0x3F80;  // bf16 1.0

  auto do_stage = [&](int j, int bf) {
    #pragma unroll
    for (int p = 0; p < 2; p++) {          // K: 8 segs of 1024B (8 rows x 64)
      const int seg = w*2 + p;             // 0..7
      const int r = seg*8 + (lane >> 3);   // kv row 0..63
      const int g = (lane & 7) ^ (r & 7);
      gl_lds16(kg + bh + (j*64 + r) * 1024 + g*8, &K_lds[bf][seg*512]);
    }
    #pragma unroll
    for (int p = 0; p < 2; p++) {          // Vt: 8 segs of 8 d-rows x 64
      const int seg = w*2 + p;
      const int r = seg*8 + (lane >> 3);   // d row 0..63
      const int g = (lane & 7) ^ (r & 7);
      gl_lds16(vtg + vtb + r * 2048 + j*64 + g*8, &V_lds[bf][seg*512]);
    }
  };

  do_stage(0, 0);
  for (int j = 0; j <= t; j++) {
    __syncthreads();                       // stripe j landed; other buf free
    if (j < t) do_stage(j + 1, (j + 1) & 1);
    const int bf = j & 1;
    const bool diag = (j == t);

    // fused per-32-k-chunk pipeline: S^T -> mask -> exp2 -> pack -> PV
    #pragma unroll
    for (int ss = 0; ss < 2; ss++) {
      // ---- S^T = K Q^T for nt = 2ss, 2ss+1
      f32x4 s[2];
      #pragma unroll
      for (int h = 0; h < 2; h++) {
        const int nt = ss*2 + h;
        const int krow = (nt*16 + l15) * 64;
        const int g0 = ((quad)     ^ (l15 & 7)) * 8;
        const int g1 = ((4 + quad) ^ (l15 & 7)) * 8;
        bf16x8 kf0 = *(const bf16x8*)&K_lds[bf][krow + g0];
        bf16x8 kf1 = *(const bf16x8*)&K_lds[bf][krow + g1];
        __builtin_amdgcn_s_setprio(1);
        f32x4 z = {};
        z = __builtin_amdgcn_mfma_f32_16x16x32_bf16(kf0, qf[0], z, 0, 0, 0);
        z = __builtin_amdgcn_mfma_f32_16x16x32_bf16(kf1, qf[1], z, 0, 0, 0);
        s[h] = z;
        __builtin_amdgcn_s_setprio(0);
      }
      if (diag) {
        const int qr = w*16 + l15;         // q-local (col axis of S^T)
        #pragma unroll
        for (int h = 0; h < 2; h++)
          #pragma unroll
          for (int r = 0; r < 4; r++)
            if ((ss*2 + h)*16 + quad*4 + r > qr) s[h][r] = -1e30f;
      }
      // ---- p = exp2(s); pack to PV A-frag in-register (no LDS)
      float a0 = __builtin_amdgcn_exp2f(s[0][0]), a1 = __builtin_amdgcn_exp2f(s[0][1]);
      float a2 = __builtin_amdgcn_exp2f(s[0][2]), a3 = __builtin_amdgcn_exp2f(s[0][3]);
      float b0 = __builtin_amdgcn_exp2f(s[1][0]), b1 = __builtin_amdgcn_exp2f(s[1][1]);
      float b2 = __builtin_amdgcn_exp2f(s[1][2]), b3 = __builtin_amdgcn_exp2f(s[1][3]);
      unsigned A01 = pk2bf(a0, a1), A23 = pk2bf(a2, a3);
      unsigned B01 = pk2bf(b0, b1), B23 = pk2bf(b2, b3);
      // permlane32_swap: r0=[X_lo,Y_lo], r1=[X_hi,Y_hi]
      // permlane16_swap: r0=[Xq0,Yq0,Xq2,Yq2], r1=[Xq1,Yq1,Xq3,Yq3]
      u32x2 t0 = __builtin_amdgcn_permlane32_swap(A01, B01, false, false);
      u32x2 w02 = __builtin_amdgcn_permlane16_swap(t0[0], t0[1], false, false);
      u32x2 t1 = __builtin_amdgcn_permlane32_swap(A23, B23, false, false);
      u32x2 w13 = __builtin_amdgcn_permlane16_swap(t1[0], t1[1], false, false);
      union { unsigned u[4]; bf16x8 v; } pk;
      pk.u[0] = w02[0]; pk.u[1] = w13[0]; pk.u[2] = w02[1]; pk.u[3] = w13[1];
      bf16x8 pa = pk.v;
      // ---- O += P V ; l += P 1
      __builtin_amdgcn_s_setprio(1);
      l5 = __builtin_amdgcn_mfma_f32_16x16x32_bf16(pa, ones, l5, 0, 0, 0);
      #pragma unroll
      for (int dt = 0; dt < 4; dt++) {
        const int vg = ((ss*4 + quad) ^ (l15 & 7)) * 8;
        bf16x8 vf = *(const bf16x8*)&V_lds[bf][(dt*16 + l15)*64 + vg];
        o[dt] = __builtin_amdgcn_mfma_f32_16x16x32_bf16(pa, vf, o[dt], 0, 0, 0);
      }
      __builtin_amdgcn_s_setprio(0);
    }
  }

  #pragma unroll
  for (int r = 0; r < 4; r++) {
    float inv = 1.0f / l5[r];
    u16* yr = &yg[bh + (t*64 + w*16 + quad*4 + r) * 1024 + l15];
    st2bf(yr,      yr + 16, o[0][r] * inv, o[1][r] * inv);
    st2bf(yr + 32, yr + 48, o[2][r] * inv, o[3][r] * inv);
  }
}

extern "C" void kernel_launch(void* const* d_in, const int* in_sizes, int n_in,
                              void* d_out, int out_size, void* d_ws, size_t ws_size,
                              hipStream_t stream) {
  const float* x  = (const float*)d_in[0];
  const float* Wq = (const float*)d_in[1];
  const float* bq = (const float*)d_in[2];
  const float* Wk = (const float*)d_in[3];
  const float* bk = (const float*)d_in[4];
  const float* Wv = (const float*)d_in[5];
  const float* bv = (const float*)d_in[6];
  const float* Wp = (const float*)d_in[7];
  const float* bp = (const float*)d_in[8];

  char* ws = (char*)d_ws;
  u16* xb  = (u16*)(ws);                   // 8 MB, reused as attention output y
  u16* wqb = (u16*)(ws + (8u  << 20));
  u16* wkb = (u16*)(ws + (10u << 20));
  u16* wvb = (u16*)(ws + (12u << 20));
  u16* wpb = (u16*)(ws + (14u << 20));
  u16* qb  = (u16*)(ws + (16u << 20));
  u16* kb  = (u16*)(ws + (24u << 20));
  u16* vtb = (u16*)(ws + (32u << 20));     // V transposed: [b,h,d][t], 8 MB
  float2* tab = (float2*)(ws + (40u << 20));
  u16* yb = xb;

  convert_kernel<<<8448, 256, 0, stream>>>((const float4*)x, (const float4*)Wq, (const float4*)Wk,
                                           (const float4*)Wv, (const float4*)Wp,
                                           xb, wqb, wkb, wvb, wpb, tab);
  gemm_bt_kernel<1, 1, 1, 128, 128, 32, 3><<<dim3(8, 32, 3), 256, 0, stream>>>(
      xb, wqb, wkb, wvb, bq, bk, bv, (void*)qb, (void*)kb, (void*)vtb, tab);
  attn_kernel<<<dim3(32, 16, 2), 256, 0, stream>>>(qb, kb, vtb, yb);
  gemm_bt_kernel<0, 0, 0, 128, 64, 64, 1><<<dim3(16, 32, 1), 256, 0, stream>>>(
      yb, wpb, wpb, wpb, bp, bp, bp, (void*)d_out, (void*)d_out, (void*)d_out, tab);
}

// Round 11
// 182.599 us; speedup vs baseline: 1.0297x; 1.0030x over previous
//
#include <hip/hip_runtime.h>
#include <hip/hip_bf16.h>
#include <stdint.h>

typedef unsigned short u16;
typedef __attribute__((ext_vector_type(8))) short bf16x8;
typedef __attribute__((ext_vector_type(4))) float f32x4;
typedef __attribute__((ext_vector_type(2))) unsigned int u32x2;

typedef const __attribute__((address_space(1))) unsigned int* gu32p;
typedef __attribute__((address_space(3))) unsigned int* lu32p;

__device__ __forceinline__ void gl_lds16(const u16* g, u16* l) {
  // async global->LDS DMA, 16B/lane, LDS dest = wave-uniform base + lane*16
  __builtin_amdgcn_global_load_lds((gu32p)(const void*)g, (lu32p)(void*)l, 16, 0, 0);
}

template<int N> __device__ __forceinline__ void wait_vmcnt() {
  if constexpr (N == 0)      asm volatile("s_waitcnt vmcnt(0)" ::: "memory");
  else if constexpr (N == 3) asm volatile("s_waitcnt vmcnt(3)" ::: "memory");
  else if constexpr (N == 4) asm volatile("s_waitcnt vmcnt(4)" ::: "memory");
  else if constexpr (N == 5) asm volatile("s_waitcnt vmcnt(5)" ::: "memory");
  else                       asm volatile("s_waitcnt vmcnt(6)" ::: "memory");
}

__device__ __forceinline__ u16 f2bf(float f) {
  union { float f; unsigned u; } v; v.f = f;
  unsigned r = v.u + 0x7fffu + ((v.u >> 16) & 1u);
  return (u16)(r >> 16);
}
// packed f32x2 -> bf16x2 (one v_cvt_pk), scattered to two u16 slots
__device__ __forceinline__ void st2bf(u16* p0, u16* p1, float a, float b) {
  union { __hip_bfloat162 h; u16 u[2]; } cv;
  cv.h = __float22bfloat162_rn(make_float2(a, b));
  *p0 = cv.u[0]; *p1 = cv.u[1];
}
// packed f32x2 -> bf16x2 as one u32 word (low = a, high = b)
__device__ __forceinline__ unsigned pk2bf(float a, float b) {
  union { __hip_bfloat162 h; unsigned u; } cv;
  cv.h = __float22bfloat162_rn(make_float2(a, b));
  return cv.u;
}

// ---------------- fp32 -> bf16 convert (x + 4 weights) and RoPE cos/sin table
__global__ void convert_kernel(const float4* __restrict__ x, const float4* __restrict__ wq,
                               const float4* __restrict__ wk, const float4* __restrict__ wv,
                               const float4* __restrict__ wp,
                               u16* __restrict__ xb, u16* __restrict__ wqb, u16* __restrict__ wkb,
                               u16* __restrict__ wvb, u16* __restrict__ wpb,
                               float2* __restrict__ tab) {
  int i = blockIdx.x * 256 + threadIdx.x;
  const int NX = 1048576, NW = 262144, NCONV = NX + 4 * NW;
  if (i >= NCONV) {
    int j = i - NCONV;              // 0..65535 : t*32 + d
    int d = j & 31, t = j >> 5;
    float ang = (float)t * expf(-0.28782313662425572f * (float)d);  // ln(10000)/32
    tab[j] = make_float2(cosf(ang), sinf(ang));
    return;
  }
  const float4* src; u16* dst; int off;
  if (i < NX)            { src = x;  dst = xb;  off = i; }
  else if (i < NX + NW)  { src = wq; dst = wqb; off = i - NX; }
  else if (i < NX + 2*NW){ src = wk; dst = wkb; off = i - NX - NW; }
  else if (i < NX + 3*NW){ src = wv; dst = wvb; off = i - NX - 2*NW; }
  else                   { src = wp; dst = wpb; off = i - NX - 3*NW; }
  float4 v = src[off];
  ushort4 ov = make_ushort4(f2bf(v.x), f2bf(v.y), f2bf(v.z), f2bf(v.w));
  *(ushort4*)&dst[off * 4] = ov;
}

// ---------------- R11: FUSED QKV GEMM. One block computes Q, K, V for the
// same (128-row x 64-col) tile: A (x) staged ONCE for all three weight
// panels. R9/R10 cost model: per-CU time = MFMA floor + LDS floor +
// events x ~625cyc event cost. Fusing cuts events/CU 96 -> 64 (2 blocks/CU
// x 32 steps vs 3 x 32) and LDS reads/CU-step 96 -> 80 b128, while keeping
// the R7-proven counted-vmcnt 3-deep pipeline verbatim (LOADS=5, vmcnt(5)).
// Column mapping col = n0 + nt*32 + wc*16 + l15 keeps the RoPE pair
// (d, d+32) inside one wave (nt=0 holds d, nt=1 holds d+32).
// LDS 60KB -> exactly 2 blocks/CU; grid (16,32) = 512 = 2/CU uniform.
// T1 bijective XCD swizzle (nwg=512); T2-lite granule swizzle as R5 (0 conflicts).
// Epilogues: Q -> RoPE + (1/sqrt(64))*log2(e) prescale; K -> RoPE;
// V -> transposed store Vt[(b*1024+c)*2048 + t].
__global__ __launch_bounds__(256) void gemm_qkv_fused(
    const u16* __restrict__ A,
    const u16* __restrict__ W0, const u16* __restrict__ W1, const u16* __restrict__ W2,
    const float* __restrict__ bq, const float* __restrict__ bk, const float* __restrict__ bv,
    u16* __restrict__ qo, u16* __restrict__ ko, u16* __restrict__ vto,
    const float2* __restrict__ tab)
{
  __shared__ __align__(16) u16 As[3][128 * 32];      // 8 KB / buf
  __shared__ __align__(16) u16 Bs[3][3 * 64 * 32];   // 12 KB / buf (3 heads)

  // T1 XCD swizzle: contiguous chunk of new ids per XCD (nwg = 512)
  const int wgid = blockIdx.x + 16 * blockIdx.y;
  const int swz = (wgid & 7) * 64 + (wgid >> 3);
  const int bx = swz & 15, by = swz >> 4;

  const int tid = threadIdx.x, lane = tid & 63, w = tid >> 6;
  const int wr = w >> 1, wc = w & 1;
  const int quad = lane >> 4, l15 = lane & 15;
  const int m0 = by * 128, n0 = bx * 64;
  const int sr = lane >> 2;                              // staging row (16B/lane)
  const int sg = ((lane & 3) ^ ((lane >> 3) & 3)) * 8;   // pre-swizzled src granule
  const int rg4 = (l15 >> 1) & 3;                        // read-side XOR key

  auto stg = [&](int kt, int bf) {
    const int k0 = kt * 32;
    #pragma unroll
    for (int p = 0; p < 2; p++)
      gl_lds16(A + (m0 + p*64 + w*16 + sr) * 1024 + k0 + sg, &As[bf][p*2048 + w*512]);
    gl_lds16(W0 + (n0 + w*16 + sr) * 1024 + k0 + sg, &Bs[bf][0*2048 + w*512]);
    gl_lds16(W1 + (n0 + w*16 + sr) * 1024 + k0 + sg, &Bs[bf][1*2048 + w*512]);
    gl_lds16(W2 + (n0 + w*16 + sr) * 1024 + k0 + sg, &Bs[bf][2*2048 + w*512]);
  };

  f32x4 acc[4][6] = {};          // [mt][zz*2 + nt]
  stg(0, 0);
  stg(1, 1);
  int cur = 0;
  for (int kt = 0; kt < 32; kt++) {
    __builtin_amdgcn_sched_barrier(0);
    if (kt < 31) wait_vmcnt<5>();     // stage-k landed; k+1 stays in flight
    else         wait_vmcnt<0>();
    __builtin_amdgcn_sched_barrier(0);
    __builtin_amdgcn_s_barrier();
    __builtin_amdgcn_sched_barrier(0);
    if (kt < 30) stg(kt + 2, cur == 0 ? 2 : cur - 1);   // buf (kt+2)%3
    const int bf = cur;
    bf16x8 af[4], bfr[6];
    #pragma unroll
    for (int mt = 0; mt < 4; mt++)
      af[mt] = *(const bf16x8*)&As[bf][(wr*64 + mt*16 + l15) * 32 + (quad ^ rg4) * 8];
    #pragma unroll
    for (int zz = 0; zz < 3; zz++)
      #pragma unroll
      for (int nt = 0; nt < 2; nt++)
        bfr[zz*2+nt] = *(const bf16x8*)&Bs[bf][zz*2048 + (nt*32 + wc*16 + l15) * 32 + (quad ^ rg4) * 8];
    #pragma unroll
    for (int mt = 0; mt < 4; mt++)
      #pragma unroll
      for (int f = 0; f < 6; f++)
        acc[mt][f] = __builtin_amdgcn_mfma_f32_16x16x32_bf16(af[mt], bfr[f], acc[mt][f], 0, 0, 0);
    cur = (cur == 2) ? 0 : cur + 1;
  }

  // ---- epilogue: Q and K with fused RoPE (pair d / d+32 is nt=0 / nt=1)
  const int d = wc*16 + l15;
  #pragma unroll
  for (int zz = 0; zz < 2; zz++) {
    u16* outp = zz ? ko : qo;
    const float* bias = zz ? bk : bq;
    const float b0 = bias[n0 + d], b1 = bias[n0 + 32 + d];
    #pragma unroll
    for (int mt = 0; mt < 4; mt++)
      #pragma unroll
      for (int r = 0; r < 4; r++) {
        const int row = m0 + wr*64 + mt*16 + quad*4 + r;
        const int t = row & 2047;
        float2 cs = tab[t*32 + d];
        float x0 = acc[mt][zz*2+0][r] + b0;
        float x1 = acc[mt][zz*2+1][r] + b1;
        float v0 = x0 * cs.x - x1 * cs.y;
        float v1 = x1 * cs.x + x0 * cs.y;
        if (zz == 0) {                 // fold (1/sqrt(64))*log2(e) into Q
          const float SC = 0.18033688011112042f;
          v0 *= SC; v1 *= SC;
        }
        outp[row * 1024 + n0 + d]      = f2bf(v0);
        outp[row * 1024 + n0 + 32 + d] = f2bf(v1);
      }
  }
  // ---- epilogue: V transposed store (lane holds 4 consecutive t for col c)
  {
    const int bb = m0 >> 11, tg0 = (m0 & 2047) + wr*64 + quad*4;
    #pragma unroll
    for (int nt = 0; nt < 2; nt++) {
      const int c = n0 + nt*32 + wc*16 + l15;
      const float bvv = bv[c];
      u16* vrow = vto + (size_t)(bb*1024 + c) * 2048 + tg0;
      #pragma unroll
      for (int mt = 0; mt < 4; mt++) {
        ushort4 pk;
        pk.x = f2bf(acc[mt][4+nt][0] + bvv); pk.y = f2bf(acc[mt][4+nt][1] + bvv);
        pk.z = f2bf(acc[mt][4+nt][2] + bvv); pk.w = f2bf(acc[mt][4+nt][3] + bvv);
        *(ushort4*)&vrow[mt*16] = pk;
      }
    }
  }
}

// ---------------- NT GEMM (proj): C[M,N] = A[M,K] * B[N,K]^T + bias.
// Tile BM x BN (wave grid 2x2), K-step BK. T4 counted-vmcnt 3-deep pipeline —
// triple-buffered LDS, raw s_barrier, NEVER vmcnt(0) in the main loop
// (R7: QKV 46.8 -> 42.4 us). R10: proj BK=64 halves barrier events and
// doubles compute/event (R9: proj was 203 TF with 8 MFMA/step). 72KB -> 2/CU.
// T1: bijective XCD swizzle. T2-lite swizzles (conflicts 0, R5):
//   BK=64: granule (kk*4+quad)^(l15&7), src pre-swizzled (lane&7)^(lane>>3).
template<int OUT_BF16, int BM, int BN, int BK, int NZ>
__global__ __launch_bounds__(256) void gemm_bt_kernel(
    const u16* __restrict__ A, const u16* __restrict__ B0,
    const float* __restrict__ bias0, void* out0)
{
  const int MT = BM / 32, NT = BN / 32;       // per-wave frags (wave grid 2x2)
  const int LOADS = (BK == 32) ? (BM/64 + BN/64) : (BM/32 + BN/32);
  const int NSTEP = 1024 / BK;
  __shared__ __align__(16) u16 As[3][BM * BK];
  __shared__ __align__(16) u16 Bs[3][BN * BK];

  const int NXg = 1024 / BN, NYg = 4096 / BM;
  const int nwg = NXg * NYg * NZ;
  const int wgid = blockIdx.x + NXg * (blockIdx.y + NYg * blockIdx.z);
  const int swz = (wgid & 7) * (nwg >> 3) + (wgid >> 3);
  const int bx = swz % NXg, by = (swz / NXg) % NYg;

  const u16* Bw = B0;
  const float* bias = bias0;
  void* outv = out0;
  const int tid = threadIdx.x, lane = tid & 63, w = tid >> 6;
  const int wr = w >> 1, wc = w & 1;
  const int quad = lane >> 4, l15 = lane & 15;
  const int m0 = by * BM, n0 = bx * BN;
  const int sr = lane >> 2;                              // BK=32 staging row
  const int sg = ((lane & 3) ^ ((lane >> 3) & 3)) * 8;   // BK=32 src granule
  const int sr64 = lane >> 3;                            // BK=64 staging row
  const int sg64 = ((lane & 7) ^ (lane >> 3)) * 8;       // BK=64 src granule
  const int rg4 = (l15 >> 1) & 3;                        // BK=32 read XOR key

  auto stg = [&](int kt, int bf) {
    const int k0 = kt * BK;
    if constexpr (BK == 32) {
      #pragma unroll
      for (int p = 0; p < BM/64; p++)
        gl_lds16(A  + (m0 + p*64 + w*16 + sr) * 1024 + k0 + sg, &As[bf][p*2048 + w*512]);
      #pragma unroll
      for (int p = 0; p < BN/64; p++)
        gl_lds16(Bw + (n0 + p*64 + w*16 + sr) * 1024 + k0 + sg, &Bs[bf][p*2048 + w*512]);
    } else {
      #pragma unroll
      for (int p = 0; p < BM/32; p++)
        gl_lds16(A  + (m0 + p*32 + w*8 + sr64) * 1024 + k0 + sg64, &As[bf][p*2048 + w*512]);
      #pragma unroll
      for (int p = 0; p < BN/32; p++)
        gl_lds16(Bw + (n0 + p*32 + w*8 + sr64) * 1024 + k0 + sg64, &Bs[bf][p*2048 + w*512]);
    }
  };

  f32x4 acc[MT][NT] = {};
  stg(0, 0);
  stg(1, 1);
  int cur = 0;
  for (int kt = 0; kt < NSTEP; kt++) {
    __builtin_amdgcn_sched_barrier(0);
    if (kt < NSTEP-1) wait_vmcnt<LOADS>();  // stage-k landed; k+1 in flight
    else              wait_vmcnt<0>();
    __builtin_amdgcn_sched_barrier(0);
    __builtin_amdgcn_s_barrier();
    __builtin_amdgcn_sched_barrier(0);
    if (kt < NSTEP-2) stg(kt + 2, cur == 0 ? 2 : cur - 1);   // buf (kt+2)%3
    const int bf = cur;
    if constexpr (BK == 32) {
      bf16x8 af[MT], bfr[NT];
      #pragma unroll
      for (int mt = 0; mt < MT; mt++)
        af[mt] = *(const bf16x8*)&As[bf][(wr*(BM/2) + mt*16 + l15) * 32 + (quad ^ rg4) * 8];
      #pragma unroll
      for (int nt = 0; nt < NT; nt++)
        bfr[nt] = *(const bf16x8*)&Bs[bf][(wc*(BN/2) + nt*16 + l15) * 32 + (quad ^ rg4) * 8];
      #pragma unroll
      for (int mt = 0; mt < MT; mt++)
        #pragma unroll
        for (int nt = 0; nt < NT; nt++)
          acc[mt][nt] = __builtin_amdgcn_mfma_f32_16x16x32_bf16(af[mt], bfr[nt], acc[mt][nt], 0, 0, 0);
    } else {
      #pragma unroll
      for (int kk = 0; kk < 2; kk++) {
        bf16x8 af[MT], bfr[NT];
        #pragma unroll
        for (int mt = 0; mt < MT; mt++)
          af[mt] = *(const bf16x8*)&As[bf][(wr*(BM/2) + mt*16 + l15) * 64 + ((kk*4 + quad) ^ (l15 & 7)) * 8];
        #pragma unroll
        for (int nt = 0; nt < NT; nt++)
          bfr[nt] = *(const bf16x8*)&Bs[bf][(wc*(BN/2) + nt*16 + l15) * 64 + ((kk*4 + quad) ^ (l15 & 7)) * 8];
        #pragma unroll
        for (int mt = 0; mt < MT; mt++)
          #pragma unroll
          for (int nt = 0; nt < NT; nt++)
            acc[mt][nt] = __builtin_amdgcn_mfma_f32_16x16x32_bf16(af[mt], bfr[nt], acc[mt][nt], 0, 0, 0);
      }
    }
    cur = (cur == 2) ? 0 : cur + 1;
  }

  #pragma unroll
  for (int mt = 0; mt < MT; mt++) {
    #pragma unroll
    for (int r = 0; r < 4; r++) {
      const int row = m0 + wr*(BM/2) + mt*16 + quad*4 + r;
      float v[NT];
      #pragma unroll
      for (int nt = 0; nt < NT; nt++)
        v[nt] = acc[mt][nt][r] + bias[n0 + wc*(BN/2) + nt*16 + l15];
      #pragma unroll
      for (int nt = 0; nt < NT; nt++) {
        const int col = n0 + wc*(BN/2) + nt*16 + l15;
        if (OUT_BF16) ((u16*)outv)[row * 1024 + col] = f2bf(v[nt]);
        else          ((float*)outv)[row * 1024 + col] = v[nt];
      }
    }
  }
}

// ---------------- causal flash attention. R9: one 64-row q-tile per 4-wave
// block, KVBLK=64, LDS 32KB/block -> grid (32,16,2) = 1024 blocks = FOUR
// blocks/CU = 4 waves/SIMD (2x TLP; attn 45.2 -> <42.2 us). 4 independent
// barrier domains overlap each other's stage drains.
// Balance: co-resident {c,c+256,c+512,c+768} -> tiles {31-x,31-x,x,x} via
// t = b ? x : 31-x -> 66 stripes per CU uniformly.
// Plain __syncthreads + double buffer (R8: counted-vmcnt is NULL for attn).
//
// T12 (in-register P): QK^T computed with SWAPPED operands, mfma(K, Q):
// D transposes to S[q=l15][k=nt*16+quad*4+r]; permlane32_swap +
// permlane16_swap repack straight into the PV A-frag. P never touches LDS.
// Q arrives pre-scaled by (1/sqrt(64))*log2(e) (GEMM epilogue), so
// p = exp2(s) directly via __builtin_amdgcn_exp2f (bare v_exp_f32).
// T5: s_setprio(1) around MFMA clusters.
__global__ __launch_bounds__(256) void attn_kernel(
    const u16* __restrict__ qg, const u16* __restrict__ kg,
    const u16* __restrict__ vtg, u16* __restrict__ yg)
{
  __shared__ __align__(16) u16 K_lds[2][64 * 64];      // [s][d], swizzle g^(s&7)
  __shared__ __align__(16) u16 V_lds[2][64 * 64];      // [d][s], swizzle g^(d&7)
  const int x = blockIdx.x;                // 0..31
  const int hh = blockIdx.y, b = blockIdx.z;
  const int t = b ? x : (31 - x);          // heavy/light complement per CU slot
  const int tid = threadIdx.x, lane = tid & 63, w = tid >> 6;   // w: 0..3
  const int quad = lane >> 4, l15 = lane & 15;
  const int bh = b * (2048 * 1024) + hh * 64;
  const int vtb = (b * 16 + hh) * 131072;  // Vt: [b,h][64 d][2048 t]

  bf16x8 qf[2];                            // wave owns 16 q-rows: t*64+w*16+l15
  const int qrow = t*64 + w*16 + l15;
  qf[0] = *(const bf16x8*)&qg[bh + qrow*1024 + quad*8];
  qf[1] = *(const bf16x8*)&qg[bh + qrow*1024 + 32 + quad*8];

  f32x4 o[4] = {};        // [dt] un-normalized output
  f32x4 l5 = {};          // row-sum accumulator (replicated across cols)

  bf16x8 ones;
  #pragma unroll
  for (int i2 = 0; i2 < 8; i2++) ones[i2] = (short)0x3F80;  // bf16 1.0

  auto do_stage = [&](int j, int bf) {
    #pragma unroll
    for (int p = 0; p < 2; p++) {          // K: 8 segs of 1024B (8 rows x 64)
      const int seg = w*2 + p;             // 0..7
      const int r = seg*8 + (lane >> 3);   // kv row 0..63
      const int g = (lane & 7) ^ (r & 7);
      gl_lds16(kg + bh + (j*64 + r) * 1024 + g*8, &K_lds[bf][seg*512]);
    }
    #pragma unroll
    for (int p = 0; p < 2; p++) {          // Vt: 8 segs of 8 d-rows x 64
      const int seg = w*2 + p;
      const int r = seg*8 + (lane >> 3);   // d row 0..63
      const int g = (lane & 7) ^ (r & 7);
      gl_lds16(vtg + vtb + r * 2048 + j*64 + g*8, &V_lds[bf][seg*512]);
    }
  };

  do_stage(0, 0);
  for (int j = 0; j <= t; j++) {
    __syncthreads();                       // stripe j landed; other buf free
    if (j < t) do_stage(j + 1, (j + 1) & 1);
    const int bf = j & 1;
    const bool diag = (j == t);

    // fused per-32-k-chunk pipeline: S^T -> mask -> exp2 -> pack -> PV
    #pragma unroll
    for (int ss = 0; ss < 2; ss++) {
      // ---- S^T = K Q^T for nt = 2ss, 2ss+1
      f32x4 s[2];
      #pragma unroll
      for (int h = 0; h < 2; h++) {
        const int nt = ss*2 + h;
        const int krow = (nt*16 + l15) * 64;
        const int g0 = ((quad)     ^ (l15 & 7)) * 8;
        const int g1 = ((4 + quad) ^ (l15 & 7)) * 8;
        bf16x8 kf0 = *(const bf16x8*)&K_lds[bf][krow + g0];
        bf16x8 kf1 = *(const bf16x8*)&K_lds[bf][krow + g1];
        __builtin_amdgcn_s_setprio(1);
        f32x4 z = {};
        z = __builtin_amdgcn_mfma_f32_16x16x32_bf16(kf0, qf[0], z, 0, 0, 0);
        z = __builtin_amdgcn_mfma_f32_16x16x32_bf16(kf1, qf[1], z, 0, 0, 0);
        s[h] = z;
        __builtin_amdgcn_s_setprio(0);
      }
      if (diag) {
        const int qr = w*16 + l15;         // q-local (col axis of S^T)
        #pragma unroll
        for (int h = 0; h < 2; h++)
          #pragma unroll
          for (int r = 0; r < 4; r++)
            if ((ss*2 + h)*16 + quad*4 + r > qr) s[h][r] = -1e30f;
      }
      // ---- p = exp2(s); pack to PV A-frag in-register (no LDS)
      float a0 = __builtin_amdgcn_exp2f(s[0][0]), a1 = __builtin_amdgcn_exp2f(s[0][1]);
      float a2 = __builtin_amdgcn_exp2f(s[0][2]), a3 = __builtin_amdgcn_exp2f(s[0][3]);
      float b0 = __builtin_amdgcn_exp2f(s[1][0]), b1 = __builtin_amdgcn_exp2f(s[1][1]);
      float b2 = __builtin_amdgcn_exp2f(s[1][2]), b3 = __builtin_amdgcn_exp2f(s[1][3]);
      unsigned A01 = pk2bf(a0, a1), A23 = pk2bf(a2, a3);
      unsigned B01 = pk2bf(b0, b1), B23 = pk2bf(b2, b3);
      // permlane32_swap: r0=[X_lo,Y_lo], r1=[X_hi,Y_hi]
      // permlane16_swap: r0=[Xq0,Yq0,Xq2,Yq2], r1=[Xq1,Yq1,Xq3,Yq3]
      u32x2 t0 = __builtin_amdgcn_permlane32_swap(A01, B01, false, false);
      u32x2 w02 = __builtin_amdgcn_permlane16_swap(t0[0], t0[1], false, false);
      u32x2 t1 = __builtin_amdgcn_permlane32_swap(A23, B23, false, false);
      u32x2 w13 = __builtin_amdgcn_permlane16_swap(t1[0], t1[1], false, false);
      union { unsigned u[4]; bf16x8 v; } pk;
      pk.u[0] = w02[0]; pk.u[1] = w13[0]; pk.u[2] = w02[1]; pk.u[3] = w13[1];
      bf16x8 pa = pk.v;
      // ---- O += P V ; l += P 1
      __builtin_amdgcn_s_setprio(1);
      l5 = __builtin_amdgcn_mfma_f32_16x16x32_bf16(pa, ones, l5, 0, 0, 0);
      #pragma unroll
      for (int dt = 0; dt < 4; dt++) {
        const int vg = ((ss*4 + quad) ^ (l15 & 7)) * 8;
        bf16x8 vf = *(const bf16x8*)&V_lds[bf][(dt*16 + l15)*64 + vg];
        o[dt] = __builtin_amdgcn_mfma_f32_16x16x32_bf16(pa, vf, o[dt], 0, 0, 0);
      }
      __builtin_amdgcn_s_setprio(0);
    }
  }

  #pragma unroll
  for (int r = 0; r < 4; r++) {
    float inv = 1.0f / l5[r];
    u16* yr = &yg[bh + (t*64 + w*16 + quad*4 + r) * 1024 + l15];
    st2bf(yr,      yr + 16, o[0][r] * inv, o[1][r] * inv);
    st2bf(yr + 32, yr + 48, o[2][r] * inv, o[3][r] * inv);
  }
}

extern "C" void kernel_launch(void* const* d_in, const int* in_sizes, int n_in,
                              void* d_out, int out_size, void* d_ws, size_t ws_size,
                              hipStream_t stream) {
  const float* x  = (const float*)d_in[0];
  const float* Wq = (const float*)d_in[1];
  const float* bq = (const float*)d_in[2];
  const float* Wk = (const float*)d_in[3];
  const float* bk = (const float*)d_in[4];
  const float* Wv = (const float*)d_in[5];
  const float* bv = (const float*)d_in[6];
  const float* Wp = (const float*)d_in[7];
  const float* bp = (const float*)d_in[8];

  char* ws = (char*)d_ws;
  u16* xb  = (u16*)(ws);                   // 8 MB, reused as attention output y
  u16* wqb = (u16*)(ws + (8u  << 20));
  u16* wkb = (u16*)(ws + (10u << 20));
  u16* wvb = (u16*)(ws + (12u << 20));
  u16* wpb = (u16*)(ws + (14u << 20));
  u16* qb  = (u16*)(ws + (16u << 20));
  u16* kb  = (u16*)(ws + (24u << 20));
  u16* vtb = (u16*)(ws + (32u << 20));     // V transposed: [b,h,d][t], 8 MB
  float2* tab = (float2*)(ws + (40u << 20));
  u16* yb = xb;

  convert_kernel<<<8448, 256, 0, stream>>>((const float4*)x, (const float4*)Wq, (const float4*)Wk,
                                           (const float4*)Wv, (const float4*)Wp,
                                           xb, wqb, wkb, wvb, wpb, tab);
  gemm_qkv_fused<<<dim3(16, 32), 256, 0, stream>>>(
      xb, wqb, wkb, wvb, bq, bk, bv, qb, kb, vtb, tab);
  attn_kernel<<<dim3(32, 16, 2), 256, 0, stream>>>(qb, kb, vtb, yb);
  gemm_bt_kernel<0, 128, 64, 64, 1><<<dim3(16, 32, 1), 256, 0, stream>>>(
      yb, wpb, bp, (void*)d_out);
}